// Round 9
// baseline (433.767 us; speedup 1.0000x reference)
//
#include <hip/hip_runtime.h>

#define NNODES 50000
#define NEDGES 800000
#define ETOT   850000   /* NEDGES + NNODES self loops */
#define IN_CH  128
#define HID    32
#define HEADS  4
#define C1     128      /* HEADS*HID */
#define NEG    0.2f
#define BNEPS  1e-5f
#define XFB2   1563     /* gemm blocks = ceil(NNODES/32) */
#define EHB    3125     /* eh blocks = NEDGES/256 */
#define WTS    160      /* WT row stride in bf16 (320B, 64B-aligned rows) */
#define XSS    136      /* xs LDS row stride in bf16 (272B, 16B-aligned, 2-way banks) */
#define NC     16       /* histogram replication factor (atomic de-contention) */

typedef __attribute__((ext_vector_type(8))) short short8;
typedef __attribute__((ext_vector_type(4))) float f32x4;

// fp32 -> bf16 (RNE)
__device__ __forceinline__ unsigned short bf16r(float f) {
    unsigned u = __float_as_uint(f);
    return (unsigned short)((u + 0x7fffu + ((u >> 16) & 1u)) >> 16);
}
// pack two fp32 -> bf16x2 (RNE), first in low 16
__device__ __forceinline__ unsigned bf16pair(float f0, float f1) {
    return (unsigned)bf16r(f0) | ((unsigned)bf16r(f1) << 16);
}
__device__ __forceinline__ float blo(unsigned u) { return __uint_as_float(u << 16); }
__device__ __forceinline__ float bhi(unsigned u) { return __uint_as_float(u & 0xffff0000u); }

// ---------------- prep: WT[n][k] = bf16(W[k][n]), n<128->Wl, else Wr --------
__global__ __launch_bounds__(256) void k_prep(const float* __restrict__ Wl,
                                              const float* __restrict__ Wr,
                                              unsigned short* __restrict__ WT) {
    int idx = blockIdx.x * 256 + threadIdx.x;     // 128 blocks -> 32768
    int mat = idx >> 14, rem = idx & 16383;
    int k = rem >> 7, n = rem & 127;
    float v = mat ? Wr[k * 128 + n] : Wl[k * 128 + n];
    WT[(size_t)(mat * 128 + n) * WTS + k] = bf16r(v);
}

// ---------------- fused: conv1 MFMA transforms (blocks 0..XFB2-1) -----------
//                  + edge_attr sum / 16-way replicated dst histogram
// GEMM: M=32 nodes/block, N=256 (Wl|Wr), K=128. A = x in LDS as bf16 hi+lo
// (split-A: only W's bf16 rounding remains). B = WT direct from global.
// Histogram: copy c=(e>>8)&15 (wave-uniform) -> 16x less per-line contention.
__global__ __launch_bounds__(256) void k_xf_eh(
    const float* __restrict__ x,
    const float* __restrict__ bl, const float* __restrict__ br,
    const unsigned short* __restrict__ WT,
    unsigned* __restrict__ xlb, float* __restrict__ xr,
    const int* __restrict__ ei, const float* __restrict__ ea,
    int* __restrict__ hist, float* __restrict__ meanbuf) {
    __shared__ short xs_s[64 * XSS];              // rows 0-31 hi, 32-63 lo
    if (blockIdx.x >= XFB2) {
        // ---- histogram (replicated) + edge_attr mean ----
        float* ls = (float*)xs_s;
        int eb = blockIdx.x - XFB2;
        int e = eb * 256 + threadIdx.x;
        int c = eb & (NC - 1);                    // == (e>>8)&15, wave-uniform
        float v = 0.f;
        if (e < NEDGES) {
            atomicAdd(&hist[c * NNODES + ei[NEDGES + e]], 1);
            v = ea[e];
        }
        #pragma unroll
        for (int o = 32; o > 0; o >>= 1) v += __shfl_down(v, o, 64);
        if ((threadIdx.x & 63) == 0) ls[threadIdx.x >> 6] = v;
        __syncthreads();
        if (threadIdx.x == 0) atomicAdd(meanbuf, ls[0] + ls[1] + ls[2] + ls[3]);
        return;
    }
    int n0g = blockIdx.x * 32;
    // ---- stage x tile: 32 nodes x 128 k, bf16 hi + lo ----
    {
        int nd = threadIdx.x >> 3, kc = (threadIdx.x & 7) * 16;
        bool valid = (n0g + nd) < NNODES;
        float xv[16];
        #pragma unroll
        for (int i = 0; i < 4; i++) {
            float4 t = valid ? ((const float4*)(x + (size_t)(n0g + nd) * IN_CH + kc))[i]
                             : make_float4(0.f, 0.f, 0.f, 0.f);
            xv[4 * i] = t.x; xv[4 * i + 1] = t.y; xv[4 * i + 2] = t.z; xv[4 * i + 3] = t.w;
        }
        unsigned hi[8], lo[8];
        #pragma unroll
        for (int i = 0; i < 8; i++) {
            unsigned short h0 = bf16r(xv[2 * i]), h1 = bf16r(xv[2 * i + 1]);
            float l0 = xv[2 * i]     - __uint_as_float(((unsigned)h0) << 16);
            float l1 = xv[2 * i + 1] - __uint_as_float(((unsigned)h1) << 16);
            hi[i] = (unsigned)h0 | ((unsigned)h1 << 16);
            lo[i] = bf16pair(l0, l1);
        }
        uint4* ph = (uint4*)&xs_s[nd * XSS + kc];
        ph[0] = make_uint4(hi[0], hi[1], hi[2], hi[3]);
        ph[1] = make_uint4(hi[4], hi[5], hi[6], hi[7]);
        uint4* pl = (uint4*)&xs_s[(nd + 32) * XSS + kc];
        pl[0] = make_uint4(lo[0], lo[1], lo[2], lo[3]);
        pl[1] = make_uint4(lo[4], lo[5], lo[6], lo[7]);
    }
    __syncthreads();
    int lane = threadIdx.x & 63;
    int lm = lane & 15, q = lane >> 4;
    int w = threadIdx.x >> 6;
    int n0 = w * 64;                               // this wave's 64 output cols
    f32x4 acc[2][4];
    #pragma unroll
    for (int mt = 0; mt < 2; mt++)
        #pragma unroll
        for (int nt = 0; nt < 4; nt++) acc[mt][nt] = (f32x4)0.f;

    #pragma unroll
    for (int ks = 0; ks < 4; ks++) {
        int k0 = ks * 32 + q * 8;
        short8 ah0 = *(const short8*)&xs_s[(lm)      * XSS + k0];
        short8 ah1 = *(const short8*)&xs_s[(16 + lm) * XSS + k0];
        short8 al0 = *(const short8*)&xs_s[(32 + lm) * XSS + k0];
        short8 al1 = *(const short8*)&xs_s[(48 + lm) * XSS + k0];
        #pragma unroll
        for (int nt = 0; nt < 4; nt++) {
            short8 bfr = *(const short8*)(WT + (size_t)(n0 + nt * 16 + lm) * WTS + k0);
            acc[0][nt] = __builtin_amdgcn_mfma_f32_16x16x32_bf16(al0, bfr, acc[0][nt], 0, 0, 0);
            acc[0][nt] = __builtin_amdgcn_mfma_f32_16x16x32_bf16(ah0, bfr, acc[0][nt], 0, 0, 0);
            acc[1][nt] = __builtin_amdgcn_mfma_f32_16x16x32_bf16(al1, bfr, acc[1][nt], 0, 0, 0);
            acc[1][nt] = __builtin_amdgcn_mfma_f32_16x16x32_bf16(ah1, bfr, acc[1][nt], 0, 0, 0);
        }
    }
    // ---- epilogue: D row=(q*4+reg), col=lm (per m89-verified C/D layout) ----
    if (w < 2) {
        #pragma unroll
        for (int nt = 0; nt < 4; nt++) {
            int ch = n0 + nt * 16 + lm;
            float bv = bl[ch];
            #pragma unroll
            for (int mt = 0; mt < 2; mt++)
                #pragma unroll
                for (int r = 0; r < 4; r++) {
                    int node = n0g + mt * 16 + q * 4 + r;
                    float val = acc[mt][nt][r] + bv;
                    float pv = __shfl_xor(val, 1);
                    if ((lm & 1) == 0 && node < NNODES)
                        xlb[(size_t)node * 64 + (ch >> 1)] = bf16pair(val, pv);
                }
        }
    } else {
        #pragma unroll
        for (int nt = 0; nt < 4; nt++) {
            int ch = n0 - 128 + nt * 16 + lm;
            float bv = br[ch];
            #pragma unroll
            for (int mt = 0; mt < 2; mt++)
                #pragma unroll
                for (int r = 0; r < 4; r++) {
                    int node = n0g + mt * 16 + q * 4 + r;
                    if (node < NNODES)
                        xr[(size_t)node * C1 + ch] = acc[mt][nt][r] + bv;
                }
        }
    }
}

// ---------------- reduce 16 histogram copies -> DEG + in-place prefix -------
// hist[c][d] becomes exclusive prefix over c (slot base within node d's list)
__global__ __launch_bounds__(256) void k_red(int* __restrict__ hist,
                                             int* __restrict__ deg) {
    int d = blockIdx.x * 256 + threadIdx.x;
    if (d >= NNODES) return;
    int s = 0;
    #pragma unroll
    for (int c = 0; c < NC; c++) {
        int v = hist[c * NNODES + d];
        hist[c * NNODES + d] = s;
        s += v;
    }
    deg[d] = s;
}

// ---------------- CSR scan: rowptr from degrees (+1 self loop each) ---------
__global__ __launch_bounds__(1024) void k_scan(const int* __restrict__ deg,
                                               int* __restrict__ rowptr) {
    __shared__ int ps[1024];
    int t = threadIdx.x;
    const int CH = (NNODES + 1023) / 1024;   // 49
    int lo = t * CH, hi = lo + CH; if (hi > NNODES) hi = NNODES; if (lo > NNODES) lo = NNODES;
    int s = 0;
    for (int i = lo; i < hi; i++) s += deg[i] + 1;   // +1 = self loop
    ps[t] = s; __syncthreads();
    for (int o = 1; o < 1024; o <<= 1) {
        int v = (t >= o) ? ps[t - o] : 0;
        __syncthreads();
        ps[t] += v;
        __syncthreads();
    }
    int base = (t == 0) ? 0 : ps[t - 1];
    for (int i = lo; i < hi; i++) { rowptr[i] = base; base += deg[i] + 1; }
    if (t == 1023) rowptr[NNODES] = ps[1023];
}

// ---------------- CSR fill: packed (src, attr) int2; slot 0 = self loop -----
// Slot = rowptr[d] + 1 + prefix[c][d] + running count within copy c.
__global__ __launch_bounds__(256) void k_fill(const int* __restrict__ ei,
                                              const float* __restrict__ ea,
                                              const int* __restrict__ rowptr,
                                              const float* __restrict__ meanbuf,
                                              int* __restrict__ hist,
                                              int2* __restrict__ cpack) {
    int e = blockIdx.x * 256 + threadIdx.x;
    if (e < NEDGES) {
        int d = ei[NEDGES + e];
        int c = (e >> 8) & (NC - 1);               // wave-uniform
        int off = atomicAdd(&hist[c * NNODES + d], 1);
        cpack[rowptr[d] + 1 + off] = make_int2(ei[e], __float_as_int(ea[e]));
    } else if (e < NEDGES + NNODES) {
        int i = e - NEDGES;
        cpack[rowptr[i]] = make_int2(i, __float_as_int(meanbuf[0] * (1.0f / NEDGES)));
    } else if (e < NEDGES + NNODES + 64) {
        cpack[ETOT + e - NEDGES - NNODES] = make_int2(0, 0);
    }
}

// ---------------- conv1 fused edge phase: no-max softmax, one wave/node -----
// lane: q=lane&31 owns channels {4q..4q+3} (uint2 bf16 gather); half h=lane>>5
// processes edges k+h. Head reduction = 8-lane xor butterfly.
__global__ __launch_bounds__(256) void k_edge1(
    const unsigned* __restrict__ xlb, const float* __restrict__ xr,
    const int* __restrict__ rowptr, const int2* __restrict__ cpack,
    const float* __restrict__ We, const float* __restrict__ att,
    float* __restrict__ out1) {
    int node = blockIdx.x * 4 + (threadIdx.x >> 6);
    if (node >= NNODES) return;
    int lane = threadIdx.x & 63;
    int q = lane & 31, h = lane >> 5;
    int r0 = rowptr[node], r1 = rowptr[node + 1];
    float4 xrv = ((const float4*)xr)[(size_t)node * 32 + q];
    float4 wev = ((const float4*)We)[q];
    float4 atv = ((const float4*)att)[q];
    const uint2* xlv = (const uint2*)xlb;      // xlv[node*32 + q] = ch 4q..4q+3

    float den = 0.f, a0 = 0.f, a1 = 0.f, a2 = 0.f, a3 = 0.f;
    int nit = (r1 - r0 + 1) >> 1;
    int k = r0 + h;
    int2 sc = cpack[k];                        // overread is pad/next-row: masked
    uint2 xv = xlv[(size_t)sc.x * 32 + q];
    for (int it = 0; it < nit; it++) {
        int2 scn = cpack[k + 2];               // unconditional prefetch (padded)
        uint2 xvn = xlv[(size_t)scn.x * 32 + q];
        bool ok = k < r1;
        float a = __int_as_float(sc.y);
        float x0 = blo(xv.x), x1 = bhi(xv.x), x2 = blo(xv.y), x3 = bhi(xv.y);
        float v0 = x0 + xrv.x + a * wev.x;  v0 = v0 > 0.f ? v0 : NEG * v0;
        float v1 = x1 + xrv.y + a * wev.y;  v1 = v1 > 0.f ? v1 : NEG * v1;
        float v2 = x2 + xrv.z + a * wev.z;  v2 = v2 > 0.f ? v2 : NEG * v2;
        float v3 = x3 + xrv.w + a * wev.w;  v3 = v3 > 0.f ? v3 : NEG * v3;
        float t = v0 * atv.x + v1 * atv.y + v2 * atv.z + v3 * atv.w;
        #pragma unroll
        for (int o = 4; o > 0; o >>= 1) t += __shfl_xor(t, o);   // 8-lane head sum
        float e = ok ? __expf(t) : 0.f;
        den += e;
        a0 = fmaf(e, x0, a0); a1 = fmaf(e, x1, a1);
        a2 = fmaf(e, x2, a2); a3 = fmaf(e, x3, a3);
        k += 2; sc = scn; xv = xvn;
    }
    den += __shfl_xor(den, 32);
    a0 += __shfl_xor(a0, 32); a1 += __shfl_xor(a1, 32);
    a2 += __shfl_xor(a2, 32); a3 += __shfl_xor(a3, 32);
    if (h == 0) {
        float rd = 1.f / den;
        ((float4*)out1)[(size_t)node * 32 + q] =
            make_float4(a0 * rd, a1 * rd, a2 * rd, a3 * rd);
    }
}

// ---------------- epilogue1: bias+BN+ReLU, then conv2 transforms ------------
__global__ __launch_bounds__(256) void k_epi1(
    const float* __restrict__ out1, const float* __restrict__ bias1,
    const float* __restrict__ g1, const float* __restrict__ b1,
    const float* __restrict__ m1, const float* __restrict__ v1,
    const float* __restrict__ Wl2, const float* __restrict__ bl2,
    const float* __restrict__ Wr2, const float* __restrict__ br2,
    unsigned* __restrict__ xlb2, float* __restrict__ xr2) {
    __shared__ float hs[8 * 128];
    __shared__ float A[128], B[128];
    __shared__ float xs2[8 * 32];
    int n0 = blockIdx.x * 8;
    if (threadIdx.x < 128) {
        int c = threadIdx.x;
        float sc = g1[c] * rsqrtf(v1[c] + BNEPS);
        A[c] = sc;
        B[c] = (bias1[c] - m1[c]) * sc + b1[c];
    }
    __syncthreads();
    {
        float4 v = ((const float4*)(out1 + (size_t)n0 * C1))[threadIdx.x];
        int cb = (threadIdx.x * 4) & 127;
        float4 h;
        h.x = fmaxf(v.x * A[cb]     + B[cb],     0.f);
        h.y = fmaxf(v.y * A[cb + 1] + B[cb + 1], 0.f);
        h.z = fmaxf(v.z * A[cb + 2] + B[cb + 2], 0.f);
        h.w = fmaxf(v.w * A[cb + 3] + B[cb + 3], 0.f);
        ((float4*)hs)[threadIdx.x] = h;
    }
    __syncthreads();
    for (int o = threadIdx.x; o < 512; o += 256) {
        int node = o >> 6, rem = o & 63, mat = rem >> 5, c = rem & 31;
        const float* W = mat ? Wr2 : Wl2;
        float acc = mat ? br2[c] : bl2[c];
        const float4* hh = (const float4*)(hs + node * 128);
        #pragma unroll 8
        for (int k4 = 0; k4 < 32; k4++) {
            float4 hv = hh[k4];
            int kb = k4 * 4;
            acc += hv.x * W[kb * 32 + c]       + hv.y * W[(kb + 1) * 32 + c]
                 + hv.z * W[(kb + 2) * 32 + c] + hv.w * W[(kb + 3) * 32 + c];
        }
        if (mat) xr2[(size_t)(n0 + node) * HID + c] = acc;
        else     xs2[node * 32 + c] = acc;
    }
    __syncthreads();
    if (threadIdx.x < 128) {                 // 8 nodes x 16 bf16 pairs
        int nd = threadIdx.x >> 4, cc = threadIdx.x & 15;
        xlb2[(size_t)(n0 + nd) * 16 + cc] =
            bf16pair(xs2[nd * 32 + 2 * cc], xs2[nd * 32 + 2 * cc + 1]);
    }
}

// ---------------- conv2 fused edge phase + BN + classifier ------------------
// lane: q=lane&7 owns channels {4q..4q+3}; slot s=lane>>3 (8 edges in flight)
__global__ __launch_bounds__(256) void k_edge2(
    const unsigned* __restrict__ xlb2, const float* __restrict__ xr2,
    const int* __restrict__ rowptr, const int2* __restrict__ cpack,
    const float* __restrict__ We2, const float* __restrict__ att2,
    const float* __restrict__ bias2,
    const float* __restrict__ g2, const float* __restrict__ b2,
    const float* __restrict__ m2, const float* __restrict__ v2,
    const float* __restrict__ W, const float* __restrict__ b,
    float* __restrict__ y) {
    int node = blockIdx.x * 4 + (threadIdx.x >> 6);
    if (node >= NNODES) return;
    int lane = threadIdx.x & 63;
    int q = lane & 7, s = lane >> 3;
    int r0 = rowptr[node], r1 = rowptr[node + 1];
    float4 xrv = ((const float4*)xr2)[(size_t)node * 8 + q];
    float4 wev = ((const float4*)We2)[q];
    float4 atv = ((const float4*)att2)[q];
    const uint2* xlv = (const uint2*)xlb2;     // xlv[node*8 + q] = ch 4q..4q+3

    float den = 0.f, a0 = 0.f, a1 = 0.f, a2 = 0.f, a3 = 0.f;
    int nit = (r1 - r0 + 7) >> 3;
    int k = r0 + s;
    int2 sc = cpack[k];
    uint2 xv = xlv[(size_t)sc.x * 8 + q];
    for (int it = 0; it < nit; it++) {
        int2 scn = cpack[k + 8];               // unconditional prefetch (padded)
        uint2 xvn = xlv[(size_t)scn.x * 8 + q];
        bool ok = k < r1;
        float a = __int_as_float(sc.y);
        float x0 = blo(xv.x), x1 = bhi(xv.x), x2 = blo(xv.y), x3 = bhi(xv.y);
        float v0 = x0 + xrv.x + a * wev.x;  v0 = v0 > 0.f ? v0 : NEG * v0;
        float v1 = x1 + xrv.y + a * wev.y;  v1 = v1 > 0.f ? v1 : NEG * v1;
        float v2 = x2 + xrv.z + a * wev.z;  v2 = v2 > 0.f ? v2 : NEG * v2;
        float v3 = x3 + xrv.w + a * wev.w;  v3 = v3 > 0.f ? v3 : NEG * v3;
        float t = v0 * atv.x + v1 * atv.y + v2 * atv.z + v3 * atv.w;
        #pragma unroll
        for (int o = 4; o > 0; o >>= 1) t += __shfl_xor(t, o);   // full 32-ch sum
        float e = ok ? __expf(t) : 0.f;
        den += e;
        a0 = fmaf(e, x0, a0); a1 = fmaf(e, x1, a1);
        a2 = fmaf(e, x2, a2); a3 = fmaf(e, x3, a3);
        k += 8; sc = scn; xv = xvn;
    }
    #pragma unroll
    for (int o = 8; o <= 32; o <<= 1) {
        den += __shfl_xor(den, o);
        a0 += __shfl_xor(a0, o); a1 += __shfl_xor(a1, o);
        a2 += __shfl_xor(a2, o); a3 += __shfl_xor(a3, o);
    }
    float rd = 1.f / den;
    float4 gv = ((const float4*)g2)[q],  bv = ((const float4*)b2)[q];
    float4 mv = ((const float4*)m2)[q],  vv = ((const float4*)v2)[q];
    float4 biv = ((const float4*)bias2)[q];
    float h0 = (a0 * rd + biv.x - mv.x) * (gv.x * rsqrtf(vv.x + BNEPS)) + bv.x;
    float h1 = (a1 * rd + biv.y - mv.y) * (gv.y * rsqrtf(vv.y + BNEPS)) + bv.y;
    float h2 = (a2 * rd + biv.z - mv.z) * (gv.z * rsqrtf(vv.z + BNEPS)) + bv.z;
    float h3 = (a3 * rd + biv.w - mv.w) * (gv.w * rsqrtf(vv.w + BNEPS)) + bv.w;
    h0 = fmaxf(h0, 0.f); h1 = fmaxf(h1, 0.f); h2 = fmaxf(h2, 0.f); h3 = fmaxf(h3, 0.f);
    float4 wa = ((const float4*)W)[2 * q];       // [c0o0 c0o1 c1o0 c1o1]
    float4 wb = ((const float4*)W)[2 * q + 1];   // [c2o0 c2o1 c3o0 c3o1]
    float t0 = h0 * wa.x + h1 * wa.z + h2 * wb.x + h3 * wb.z;
    float t1 = h0 * wa.y + h1 * wa.w + h2 * wb.y + h3 * wb.w;
    #pragma unroll
    for (int o = 4; o > 0; o >>= 1) {
        t0 += __shfl_xor(t0, o);
        t1 += __shfl_xor(t1, o);
    }
    if (lane == 0) {
        y[(size_t)node * 2]     = t0 + b[0];
        y[(size_t)node * 2 + 1] = t1 + b[1];
    }
}

extern "C" void kernel_launch(void* const* d_in, const int* in_sizes, int n_in,
                              void* d_out, int out_size, void* d_ws, size_t ws_size,
                              hipStream_t stream) {
    const float* x       = (const float*)d_in[0];
    const int*   ei      = (const int*)d_in[1];
    const float* ea      = (const float*)d_in[2];
    const float* c1_Wl   = (const float*)d_in[3];
    const float* c1_bl   = (const float*)d_in[4];
    const float* c1_Wr   = (const float*)d_in[5];
    const float* c1_br   = (const float*)d_in[6];
    const float* c1_We   = (const float*)d_in[7];
    const float* c1_att  = (const float*)d_in[8];
    const float* c1_bias = (const float*)d_in[9];
    const float* bn1_g   = (const float*)d_in[10];
    const float* bn1_b   = (const float*)d_in[11];
    const float* bn1_m   = (const float*)d_in[12];
    const float* bn1_v   = (const float*)d_in[13];
    const float* c2_Wl   = (const float*)d_in[14];
    const float* c2_bl   = (const float*)d_in[15];
    const float* c2_Wr   = (const float*)d_in[16];
    const float* c2_br   = (const float*)d_in[17];
    const float* c2_We   = (const float*)d_in[18];
    const float* c2_att  = (const float*)d_in[19];
    const float* c2_bias = (const float*)d_in[20];
    const float* bn2_g   = (const float*)d_in[21];
    const float* bn2_b   = (const float*)d_in[22];
    const float* bn2_m   = (const float*)d_in[23];
    const float* bn2_v   = (const float*)d_in[24];
    const float* clf_W   = (const float*)d_in[25];
    const float* clf_b   = (const float*)d_in[26];

    float* ws = (float*)d_ws;
    size_t off = 0;
    unsigned* XLb  = (unsigned*)(ws + off); off += (size_t)NNODES * 64;  // bf16x2
    float*    XR1  = ws + off; off += (size_t)NNODES * C1;
    float*    OUT1 = ws + off; off += (size_t)NNODES * C1;
    unsigned* XLb2 = (unsigned*)(ws + off); off += (size_t)NNODES * 16;  // bf16x2
    float*    XR2  = ws + off; off += (size_t)NNODES * HID;
    int2*     CPACK= (int2*)(ws + off); off += (size_t)(ETOT + 64) * 2;
    unsigned short* WT = (unsigned short*)(ws + off); off += 256 * WTS / 2; // bf16 WT
    int*      ROWP = (int*)(ws + off); off += NNODES + 16;
    int*      DEG  = (int*)(ws + off); off += NNODES;
    int*      HIST = (int*)(ws + off); off += (size_t)NC * NNODES;  // | zeroed
    float*    MEANB= ws + off; off += 64;                           // | region
    if (ws_size < off * sizeof(float)) return;  // workspace too small: fail loudly

    hipMemsetAsync(HIST, 0, ((size_t)NC * NNODES + 64) * sizeof(int), stream);
    k_prep  <<<128, 256, 0, stream>>>(c1_Wl, c1_Wr, WT);
    k_xf_eh <<<XFB2 + EHB, 256, 0, stream>>>(x, c1_bl, c1_br, WT, XLb, XR1,
                                             ei, ea, HIST, MEANB);
    k_red   <<<(NNODES + 255) / 256, 256, 0, stream>>>(HIST, DEG);
    k_scan  <<<1, 1024, 0, stream>>>(DEG, ROWP);
    k_fill  <<<(NEDGES + NNODES + 64 + 255) / 256, 256, 0, stream>>>(ei, ea, ROWP, MEANB, HIST, CPACK);
    k_edge1 <<<(NNODES + 3) / 4, 256, 0, stream>>>(XLb, XR1, ROWP, CPACK, c1_We, c1_att, OUT1);
    k_epi1  <<<NNODES / 8, 256, 0, stream>>>(OUT1, c1_bias, bn1_g, bn1_b, bn1_m, bn1_v,
                                             c2_Wl, c2_bl, c2_Wr, c2_br, XLb2, XR2);
    k_edge2 <<<(NNODES + 3) / 4, 256, 0, stream>>>(XLb2, XR2, ROWP, CPACK, c2_We, c2_att,
                                                   c2_bias, bn2_g, bn2_b, bn2_m, bn2_v,
                                                   clf_W, clf_b, (float*)d_out);
}

// Round 10
// 359.625 us; speedup vs baseline: 1.2062x; 1.2062x over previous
//
#include <hip/hip_runtime.h>

#define NNODES 50000
#define NEDGES 800000
#define ETOT   850000   /* NEDGES + NNODES self loops */
#define IN_CH  128
#define HID    32
#define HEADS  4
#define C1     128      /* HEADS*HID */
#define NEG    0.2f
#define BNEPS  1e-5f
#define XFB2   1563     /* gemm blocks = ceil(NNODES/32) */
#define EHB    3125     /* eh blocks = NEDGES/256 */
#define WTS    160      /* WT row stride in bf16 (320B, 64B-aligned rows) */
#define XSS    136      /* xs LDS row stride in bf16 (272B, 16B-aligned, 2-way banks) */
#define NC     16       /* histogram replication factor (atomic de-contention) */
#define SCB    196      /* scan blocks = ceil(NNODES/256) */

typedef __attribute__((ext_vector_type(8))) short short8;
typedef __attribute__((ext_vector_type(4))) float f32x4;

// fp32 -> bf16 (RNE)
__device__ __forceinline__ unsigned short bf16r(float f) {
    unsigned u = __float_as_uint(f);
    return (unsigned short)((u + 0x7fffu + ((u >> 16) & 1u)) >> 16);
}
// pack two fp32 -> bf16x2 (RNE), first in low 16
__device__ __forceinline__ unsigned bf16pair(float f0, float f1) {
    return (unsigned)bf16r(f0) | ((unsigned)bf16r(f1) << 16);
}
__device__ __forceinline__ float blo(unsigned u) { return __uint_as_float(u << 16); }
__device__ __forceinline__ float bhi(unsigned u) { return __uint_as_float(u & 0xffff0000u); }

// 256-thread block inclusive scan (4 waves, shfl_up + LDS wave offsets)
__device__ __forceinline__ int block_iscan(int v, int* ls) {
    int lane = threadIdx.x & 63, w = threadIdx.x >> 6;
    #pragma unroll
    for (int o = 1; o < 64; o <<= 1) {
        int t = __shfl_up(v, o);
        if (lane >= o) v += t;
    }
    if (lane == 63) ls[w] = v;
    __syncthreads();
    int add = 0;
    #pragma unroll
    for (int i = 0; i < 4; i++) add += (i < w) ? ls[i] : 0;
    return v + add;
}

// ---------------- prep: WT[n][k] = bf16(W[k][n]), n<128->Wl, else Wr --------
__global__ __launch_bounds__(256) void k_prep(const float* __restrict__ Wl,
                                              const float* __restrict__ Wr,
                                              unsigned short* __restrict__ WT) {
    int idx = blockIdx.x * 256 + threadIdx.x;     // 128 blocks -> 32768
    int mat = idx >> 14, rem = idx & 16383;
    int k = rem >> 7, n = rem & 127;
    float v = mat ? Wr[k * 128 + n] : Wl[k * 128 + n];
    WT[(size_t)(mat * 128 + n) * WTS + k] = bf16r(v);
}

// ---------------- fused: conv1 MFMA transforms (blocks 0..XFB2-1) -----------
//                  + edge_attr sum / 16-way replicated dst histogram
__global__ __launch_bounds__(256) void k_xf_eh(
    const float* __restrict__ x,
    const float* __restrict__ bl, const float* __restrict__ br,
    const unsigned short* __restrict__ WT,
    unsigned* __restrict__ xlb, float* __restrict__ xr,
    const int* __restrict__ ei, const float* __restrict__ ea,
    int* __restrict__ hist, float* __restrict__ meanbuf) {
    __shared__ short xs_s[64 * XSS];              // rows 0-31 hi, 32-63 lo
    if (blockIdx.x >= XFB2) {
        // ---- histogram (replicated) + edge_attr mean ----
        float* ls = (float*)xs_s;
        int eb = blockIdx.x - XFB2;
        int e = eb * 256 + threadIdx.x;
        int c = eb & (NC - 1);                    // wave-uniform copy index
        float v = 0.f;
        if (e < NEDGES) {
            atomicAdd(&hist[c * NNODES + ei[NEDGES + e]], 1);
            v = ea[e];
        }
        #pragma unroll
        for (int o = 32; o > 0; o >>= 1) v += __shfl_down(v, o, 64);
        if ((threadIdx.x & 63) == 0) ls[threadIdx.x >> 6] = v;
        __syncthreads();
        if (threadIdx.x == 0) atomicAdd(meanbuf, ls[0] + ls[1] + ls[2] + ls[3]);
        return;
    }
    int n0g = blockIdx.x * 32;
    // ---- stage x tile: 32 nodes x 128 k, bf16 hi + lo ----
    {
        int nd = threadIdx.x >> 3, kc = (threadIdx.x & 7) * 16;
        bool valid = (n0g + nd) < NNODES;
        float xv[16];
        #pragma unroll
        for (int i = 0; i < 4; i++) {
            float4 t = valid ? ((const float4*)(x + (size_t)(n0g + nd) * IN_CH + kc))[i]
                             : make_float4(0.f, 0.f, 0.f, 0.f);
            xv[4 * i] = t.x; xv[4 * i + 1] = t.y; xv[4 * i + 2] = t.z; xv[4 * i + 3] = t.w;
        }
        unsigned hi[8], lo[8];
        #pragma unroll
        for (int i = 0; i < 8; i++) {
            unsigned short h0 = bf16r(xv[2 * i]), h1 = bf16r(xv[2 * i + 1]);
            float l0 = xv[2 * i]     - __uint_as_float(((unsigned)h0) << 16);
            float l1 = xv[2 * i + 1] - __uint_as_float(((unsigned)h1) << 16);
            hi[i] = (unsigned)h0 | ((unsigned)h1 << 16);
            lo[i] = bf16pair(l0, l1);
        }
        uint4* ph = (uint4*)&xs_s[nd * XSS + kc];
        ph[0] = make_uint4(hi[0], hi[1], hi[2], hi[3]);
        ph[1] = make_uint4(hi[4], hi[5], hi[6], hi[7]);
        uint4* pl = (uint4*)&xs_s[(nd + 32) * XSS + kc];
        pl[0] = make_uint4(lo[0], lo[1], lo[2], lo[3]);
        pl[1] = make_uint4(lo[4], lo[5], lo[6], lo[7]);
    }
    __syncthreads();
    int lane = threadIdx.x & 63;
    int lm = lane & 15, q = lane >> 4;
    int w = threadIdx.x >> 6;
    int n0 = w * 64;                               // this wave's 64 output cols
    f32x4 acc[2][4];
    #pragma unroll
    for (int mt = 0; mt < 2; mt++)
        #pragma unroll
        for (int nt = 0; nt < 4; nt++) acc[mt][nt] = (f32x4)0.f;

    #pragma unroll
    for (int ks = 0; ks < 4; ks++) {
        int k0 = ks * 32 + q * 8;
        short8 ah0 = *(const short8*)&xs_s[(lm)      * XSS + k0];
        short8 ah1 = *(const short8*)&xs_s[(16 + lm) * XSS + k0];
        short8 al0 = *(const short8*)&xs_s[(32 + lm) * XSS + k0];
        short8 al1 = *(const short8*)&xs_s[(48 + lm) * XSS + k0];
        #pragma unroll
        for (int nt = 0; nt < 4; nt++) {
            short8 bfr = *(const short8*)(WT + (size_t)(n0 + nt * 16 + lm) * WTS + k0);
            acc[0][nt] = __builtin_amdgcn_mfma_f32_16x16x32_bf16(al0, bfr, acc[0][nt], 0, 0, 0);
            acc[0][nt] = __builtin_amdgcn_mfma_f32_16x16x32_bf16(ah0, bfr, acc[0][nt], 0, 0, 0);
            acc[1][nt] = __builtin_amdgcn_mfma_f32_16x16x32_bf16(al1, bfr, acc[1][nt], 0, 0, 0);
            acc[1][nt] = __builtin_amdgcn_mfma_f32_16x16x32_bf16(ah1, bfr, acc[1][nt], 0, 0, 0);
        }
    }
    // ---- epilogue: D row=(q*4+reg), col=lm ----
    if (w < 2) {
        #pragma unroll
        for (int nt = 0; nt < 4; nt++) {
            int ch = n0 + nt * 16 + lm;
            float bv = bl[ch];
            #pragma unroll
            for (int mt = 0; mt < 2; mt++)
                #pragma unroll
                for (int r = 0; r < 4; r++) {
                    int node = n0g + mt * 16 + q * 4 + r;
                    float val = acc[mt][nt][r] + bv;
                    float pv = __shfl_xor(val, 1);
                    if ((lm & 1) == 0 && node < NNODES)
                        xlb[(size_t)node * 64 + (ch >> 1)] = bf16pair(val, pv);
                }
        }
    } else {
        #pragma unroll
        for (int nt = 0; nt < 4; nt++) {
            int ch = n0 - 128 + nt * 16 + lm;
            float bv = br[ch];
            #pragma unroll
            for (int mt = 0; mt < 2; mt++)
                #pragma unroll
                for (int r = 0; r < 4; r++) {
                    int node = n0g + mt * 16 + q * 4 + r;
                    if (node < NNODES)
                        xr[(size_t)node * C1 + ch] = acc[mt][nt][r] + bv;
                }
        }
    }
}

// ---------------- reduce 16 histogram copies -> DEG + per-block sums --------
// hist[c][d] becomes exclusive prefix over c; bsum[b] = sum over block of deg+1
__global__ __launch_bounds__(256) void k_red(int* __restrict__ hist,
                                             int* __restrict__ deg,
                                             int* __restrict__ bsum) {
    __shared__ int ls[4];
    int d = blockIdx.x * 256 + threadIdx.x;
    int s = 0;
    if (d < NNODES) {
        #pragma unroll
        for (int c = 0; c < NC; c++) {
            int v = hist[c * NNODES + d];
            hist[c * NNODES + d] = s;
            s += v;
        }
        deg[d] = s;
    }
    int v = (d < NNODES) ? s + 1 : 0;              // +1 = self loop
    #pragma unroll
    for (int o = 32; o > 0; o >>= 1) v += __shfl_down(v, o, 64);
    if ((threadIdx.x & 63) == 0) ls[threadIdx.x >> 6] = v;
    __syncthreads();
    if (threadIdx.x == 0) bsum[blockIdx.x] = ls[0] + ls[1] + ls[2] + ls[3];
}

// ---------------- scan the SCB block sums -> exclusive block offsets --------
__global__ __launch_bounds__(256) void k_bscan(const int* __restrict__ bsum,
                                               int* __restrict__ boff) {
    __shared__ int ls[4];
    int t = threadIdx.x;
    int v = (t < SCB) ? bsum[t] : 0;
    int incl = block_iscan(v, ls);
    if (t < SCB) boff[t] = incl - v;
}

// ---------------- rowptr: block offset + in-block exclusive scan ------------
__global__ __launch_bounds__(256) void k_rowp(const int* __restrict__ deg,
                                              const int* __restrict__ boff,
                                              int* __restrict__ rowptr) {
    __shared__ int ls[4];
    int d = blockIdx.x * 256 + threadIdx.x;
    int v = (d < NNODES) ? deg[d] + 1 : 0;
    int incl = block_iscan(v, ls);
    int base = boff[blockIdx.x];
    if (d < NNODES) rowptr[d] = base + incl - v;
    if (d == NNODES - 1) rowptr[NNODES] = base + incl;
}

// ---------------- CSR fill: packed (src, attr) int2; slot 0 = self loop -----
__global__ __launch_bounds__(256) void k_fill(const int* __restrict__ ei,
                                              const float* __restrict__ ea,
                                              const int* __restrict__ rowptr,
                                              const float* __restrict__ meanbuf,
                                              int* __restrict__ hist,
                                              int2* __restrict__ cpack) {
    int e = blockIdx.x * 256 + threadIdx.x;
    if (e < NEDGES) {
        int d = ei[NEDGES + e];
        int c = (e >> 8) & (NC - 1);               // wave-uniform
        int off = atomicAdd(&hist[c * NNODES + d], 1);
        cpack[rowptr[d] + 1 + off] = make_int2(ei[e], __float_as_int(ea[e]));
    } else if (e < NEDGES + NNODES) {
        int i = e - NEDGES;
        cpack[rowptr[i]] = make_int2(i, __float_as_int(meanbuf[0] * (1.0f / NEDGES)));
    } else if (e < NEDGES + NNODES + 64) {
        cpack[ETOT + e - NEDGES - NNODES] = make_int2(0, 0);
    }
}

// ---------------- conv1 fused edge phase: no-max softmax, one wave/node -----
__global__ __launch_bounds__(256) void k_edge1(
    const unsigned* __restrict__ xlb, const float* __restrict__ xr,
    const int* __restrict__ rowptr, const int2* __restrict__ cpack,
    const float* __restrict__ We, const float* __restrict__ att,
    float* __restrict__ out1) {
    int node = blockIdx.x * 4 + (threadIdx.x >> 6);
    if (node >= NNODES) return;
    int lane = threadIdx.x & 63;
    int q = lane & 31, h = lane >> 5;
    int r0 = rowptr[node], r1 = rowptr[node + 1];
    float4 xrv = ((const float4*)xr)[(size_t)node * 32 + q];
    float4 wev = ((const float4*)We)[q];
    float4 atv = ((const float4*)att)[q];
    const uint2* xlv = (const uint2*)xlb;      // xlv[node*32 + q] = ch 4q..4q+3

    float den = 0.f, a0 = 0.f, a1 = 0.f, a2 = 0.f, a3 = 0.f;
    int nit = (r1 - r0 + 1) >> 1;
    int k = r0 + h;
    int2 sc = cpack[k];                        // overread is pad/next-row: masked
    uint2 xv = xlv[(size_t)sc.x * 32 + q];
    for (int it = 0; it < nit; it++) {
        int2 scn = cpack[k + 2];               // unconditional prefetch (padded)
        uint2 xvn = xlv[(size_t)scn.x * 32 + q];
        bool ok = k < r1;
        float a = __int_as_float(sc.y);
        float x0 = blo(xv.x), x1 = bhi(xv.x), x2 = blo(xv.y), x3 = bhi(xv.y);
        float v0 = x0 + xrv.x + a * wev.x;  v0 = v0 > 0.f ? v0 : NEG * v0;
        float v1 = x1 + xrv.y + a * wev.y;  v1 = v1 > 0.f ? v1 : NEG * v1;
        float v2 = x2 + xrv.z + a * wev.z;  v2 = v2 > 0.f ? v2 : NEG * v2;
        float v3 = x3 + xrv.w + a * wev.w;  v3 = v3 > 0.f ? v3 : NEG * v3;
        float t = v0 * atv.x + v1 * atv.y + v2 * atv.z + v3 * atv.w;
        #pragma unroll
        for (int o = 4; o > 0; o >>= 1) t += __shfl_xor(t, o);   // 8-lane head sum
        float e = ok ? __expf(t) : 0.f;
        den += e;
        a0 = fmaf(e, x0, a0); a1 = fmaf(e, x1, a1);
        a2 = fmaf(e, x2, a2); a3 = fmaf(e, x3, a3);
        k += 2; sc = scn; xv = xvn;
    }
    den += __shfl_xor(den, 32);
    a0 += __shfl_xor(a0, 32); a1 += __shfl_xor(a1, 32);
    a2 += __shfl_xor(a2, 32); a3 += __shfl_xor(a3, 32);
    if (h == 0) {
        float rd = 1.f / den;
        ((float4*)out1)[(size_t)node * 32 + q] =
            make_float4(a0 * rd, a1 * rd, a2 * rd, a3 * rd);
    }
}

// ---------------- epilogue1: bias+BN+ReLU, then conv2 transforms ------------
__global__ __launch_bounds__(256) void k_epi1(
    const float* __restrict__ out1, const float* __restrict__ bias1,
    const float* __restrict__ g1, const float* __restrict__ b1,
    const float* __restrict__ m1, const float* __restrict__ v1,
    const float* __restrict__ Wl2, const float* __restrict__ bl2,
    const float* __restrict__ Wr2, const float* __restrict__ br2,
    unsigned* __restrict__ xlb2, float* __restrict__ xr2) {
    __shared__ float hs[8 * 128];
    __shared__ float A[128], B[128];
    __shared__ float xs2[8 * 32];
    int n0 = blockIdx.x * 8;
    if (threadIdx.x < 128) {
        int c = threadIdx.x;
        float sc = g1[c] * rsqrtf(v1[c] + BNEPS);
        A[c] = sc;
        B[c] = (bias1[c] - m1[c]) * sc + b1[c];
    }
    __syncthreads();
    {
        float4 v = ((const float4*)(out1 + (size_t)n0 * C1))[threadIdx.x];
        int cb = (threadIdx.x * 4) & 127;
        float4 h;
        h.x = fmaxf(v.x * A[cb]     + B[cb],     0.f);
        h.y = fmaxf(v.y * A[cb + 1] + B[cb + 1], 0.f);
        h.z = fmaxf(v.z * A[cb + 2] + B[cb + 2], 0.f);
        h.w = fmaxf(v.w * A[cb + 3] + B[cb + 3], 0.f);
        ((float4*)hs)[threadIdx.x] = h;
    }
    __syncthreads();
    for (int o = threadIdx.x; o < 512; o += 256) {
        int node = o >> 6, rem = o & 63, mat = rem >> 5, c = rem & 31;
        const float* W = mat ? Wr2 : Wl2;
        float acc = mat ? br2[c] : bl2[c];
        const float4* hh = (const float4*)(hs + node * 128);
        #pragma unroll 8
        for (int k4 = 0; k4 < 32; k4++) {
            float4 hv = hh[k4];
            int kb = k4 * 4;
            acc += hv.x * W[kb * 32 + c]       + hv.y * W[(kb + 1) * 32 + c]
                 + hv.z * W[(kb + 2) * 32 + c] + hv.w * W[(kb + 3) * 32 + c];
        }
        if (mat) xr2[(size_t)(n0 + node) * HID + c] = acc;
        else     xs2[node * 32 + c] = acc;
    }
    __syncthreads();
    if (threadIdx.x < 128) {                 // 8 nodes x 16 bf16 pairs
        int nd = threadIdx.x >> 4, cc = threadIdx.x & 15;
        xlb2[(size_t)(n0 + nd) * 16 + cc] =
            bf16pair(xs2[nd * 32 + 2 * cc], xs2[nd * 32 + 2 * cc + 1]);
    }
}

// ---------------- conv2 fused edge phase + BN + classifier ------------------
__global__ __launch_bounds__(256) void k_edge2(
    const unsigned* __restrict__ xlb2, const float* __restrict__ xr2,
    const int* __restrict__ rowptr, const int2* __restrict__ cpack,
    const float* __restrict__ We2, const float* __restrict__ att2,
    const float* __restrict__ bias2,
    const float* __restrict__ g2, const float* __restrict__ b2,
    const float* __restrict__ m2, const float* __restrict__ v2,
    const float* __restrict__ W, const float* __restrict__ b,
    float* __restrict__ y) {
    int node = blockIdx.x * 4 + (threadIdx.x >> 6);
    if (node >= NNODES) return;
    int lane = threadIdx.x & 63;
    int q = lane & 7, s = lane >> 3;
    int r0 = rowptr[node], r1 = rowptr[node + 1];
    float4 xrv = ((const float4*)xr2)[(size_t)node * 8 + q];
    float4 wev = ((const float4*)We2)[q];
    float4 atv = ((const float4*)att2)[q];
    const uint2* xlv = (const uint2*)xlb2;     // xlv[node*8 + q] = ch 4q..4q+3

    float den = 0.f, a0 = 0.f, a1 = 0.f, a2 = 0.f, a3 = 0.f;
    int nit = (r1 - r0 + 7) >> 3;
    int k = r0 + s;
    int2 sc = cpack[k];
    uint2 xv = xlv[(size_t)sc.x * 8 + q];
    for (int it = 0; it < nit; it++) {
        int2 scn = cpack[k + 8];               // unconditional prefetch (padded)
        uint2 xvn = xlv[(size_t)scn.x * 8 + q];
        bool ok = k < r1;
        float a = __int_as_float(sc.y);
        float x0 = blo(xv.x), x1 = bhi(xv.x), x2 = blo(xv.y), x3 = bhi(xv.y);
        float v0 = x0 + xrv.x + a * wev.x;  v0 = v0 > 0.f ? v0 : NEG * v0;
        float v1 = x1 + xrv.y + a * wev.y;  v1 = v1 > 0.f ? v1 : NEG * v1;
        float v2 = x2 + xrv.z + a * wev.z;  v2 = v2 > 0.f ? v2 : NEG * v2;
        float v3 = x3 + xrv.w + a * wev.w;  v3 = v3 > 0.f ? v3 : NEG * v3;
        float t = v0 * atv.x + v1 * atv.y + v2 * atv.z + v3 * atv.w;
        #pragma unroll
        for (int o = 4; o > 0; o >>= 1) t += __shfl_xor(t, o);   // full 32-ch sum
        float e = ok ? __expf(t) : 0.f;
        den += e;
        a0 = fmaf(e, x0, a0); a1 = fmaf(e, x1, a1);
        a2 = fmaf(e, x2, a2); a3 = fmaf(e, x3, a3);
        k += 8; sc = scn; xv = xvn;
    }
    #pragma unroll
    for (int o = 8; o <= 32; o <<= 1) {
        den += __shfl_xor(den, o);
        a0 += __shfl_xor(a0, o); a1 += __shfl_xor(a1, o);
        a2 += __shfl_xor(a2, o); a3 += __shfl_xor(a3, o);
    }
    float rd = 1.f / den;
    float4 gv = ((const float4*)g2)[q],  bv = ((const float4*)b2)[q];
    float4 mv = ((const float4*)m2)[q],  vv = ((const float4*)v2)[q];
    float4 biv = ((const float4*)bias2)[q];
    float h0 = (a0 * rd + biv.x - mv.x) * (gv.x * rsqrtf(vv.x + BNEPS)) + bv.x;
    float h1 = (a1 * rd + biv.y - mv.y) * (gv.y * rsqrtf(vv.y + BNEPS)) + bv.y;
    float h2 = (a2 * rd + biv.z - mv.z) * (gv.z * rsqrtf(vv.z + BNEPS)) + bv.z;
    float h3 = (a3 * rd + biv.w - mv.w) * (gv.w * rsqrtf(vv.w + BNEPS)) + bv.w;
    h0 = fmaxf(h0, 0.f); h1 = fmaxf(h1, 0.f); h2 = fmaxf(h2, 0.f); h3 = fmaxf(h3, 0.f);
    float4 wa = ((const float4*)W)[2 * q];       // [c0o0 c0o1 c1o0 c1o1]
    float4 wb = ((const float4*)W)[2 * q + 1];   // [c2o0 c2o1 c3o0 c3o1]
    float t0 = h0 * wa.x + h1 * wa.z + h2 * wb.x + h3 * wb.z;
    float t1 = h0 * wa.y + h1 * wa.w + h2 * wb.y + h3 * wb.w;
    #pragma unroll
    for (int o = 4; o > 0; o >>= 1) {
        t0 += __shfl_xor(t0, o);
        t1 += __shfl_xor(t1, o);
    }
    if (lane == 0) {
        y[(size_t)node * 2]     = t0 + b[0];
        y[(size_t)node * 2 + 1] = t1 + b[1];
    }
}

extern "C" void kernel_launch(void* const* d_in, const int* in_sizes, int n_in,
                              void* d_out, int out_size, void* d_ws, size_t ws_size,
                              hipStream_t stream) {
    const float* x       = (const float*)d_in[0];
    const int*   ei      = (const int*)d_in[1];
    const float* ea      = (const float*)d_in[2];
    const float* c1_Wl   = (const float*)d_in[3];
    const float* c1_bl   = (const float*)d_in[4];
    const float* c1_Wr   = (const float*)d_in[5];
    const float* c1_br   = (const float*)d_in[6];
    const float* c1_We   = (const float*)d_in[7];
    const float* c1_att  = (const float*)d_in[8];
    const float* c1_bias = (const float*)d_in[9];
    const float* bn1_g   = (const float*)d_in[10];
    const float* bn1_b   = (const float*)d_in[11];
    const float* bn1_m   = (const float*)d_in[12];
    const float* bn1_v   = (const float*)d_in[13];
    const float* c2_Wl   = (const float*)d_in[14];
    const float* c2_bl   = (const float*)d_in[15];
    const float* c2_Wr   = (const float*)d_in[16];
    const float* c2_br   = (const float*)d_in[17];
    const float* c2_We   = (const float*)d_in[18];
    const float* c2_att  = (const float*)d_in[19];
    const float* c2_bias = (const float*)d_in[20];
    const float* bn2_g   = (const float*)d_in[21];
    const float* bn2_b   = (const float*)d_in[22];
    const float* bn2_m   = (const float*)d_in[23];
    const float* bn2_v   = (const float*)d_in[24];
    const float* clf_W   = (const float*)d_in[25];
    const float* clf_b   = (const float*)d_in[26];

    float* ws = (float*)d_ws;
    size_t off = 0;
    unsigned* XLb  = (unsigned*)(ws + off); off += (size_t)NNODES * 64;  // bf16x2
    float*    XR1  = ws + off; off += (size_t)NNODES * C1;
    float*    OUT1 = ws + off; off += (size_t)NNODES * C1;
    unsigned* XLb2 = (unsigned*)(ws + off); off += (size_t)NNODES * 16;  // bf16x2
    float*    XR2  = ws + off; off += (size_t)NNODES * HID;
    int2*     CPACK= (int2*)(ws + off); off += (size_t)(ETOT + 64) * 2;
    unsigned short* WT = (unsigned short*)(ws + off); off += 256 * WTS / 2; // bf16 WT
    int*      ROWP = (int*)(ws + off); off += NNODES + 16;
    int*      DEG  = (int*)(ws + off); off += NNODES;
    int*      BSUM = (int*)(ws + off); off += 256;
    int*      BOFF = (int*)(ws + off); off += 256;
    int*      HIST = (int*)(ws + off); off += (size_t)NC * NNODES;  // | zeroed
    float*    MEANB= ws + off; off += 64;                           // | region
    if (ws_size < off * sizeof(float)) return;  // workspace too small: fail loudly

    hipMemsetAsync(HIST, 0, ((size_t)NC * NNODES + 64) * sizeof(int), stream);
    k_prep  <<<128, 256, 0, stream>>>(c1_Wl, c1_Wr, WT);
    k_xf_eh <<<XFB2 + EHB, 256, 0, stream>>>(x, c1_bl, c1_br, WT, XLb, XR1,
                                             ei, ea, HIST, MEANB);
    k_red   <<<SCB, 256, 0, stream>>>(HIST, DEG, BSUM);
    k_bscan <<<1, 256, 0, stream>>>(BSUM, BOFF);
    k_rowp  <<<SCB, 256, 0, stream>>>(DEG, BOFF, ROWP);
    k_fill  <<<(NEDGES + NNODES + 64 + 255) / 256, 256, 0, stream>>>(ei, ea, ROWP, MEANB, HIST, CPACK);
    k_edge1 <<<(NNODES + 3) / 4, 256, 0, stream>>>(XLb, XR1, ROWP, CPACK, c1_We, c1_att, OUT1);
    k_epi1  <<<NNODES / 8, 256, 0, stream>>>(OUT1, c1_bias, bn1_g, bn1_b, bn1_m, bn1_v,
                                             c2_Wl, c2_bl, c2_Wr, c2_br, XLb2, XR2);
    k_edge2 <<<(NNODES + 3) / 4, 256, 0, stream>>>(XLb2, XR2, ROWP, CPACK, c2_We, c2_att,
                                                   c2_bias, bn2_g, bn2_b, bn2_m, bn2_v,
                                                   clf_W, clf_b, (float*)d_out);
}